// Round 9
// baseline (431.346 us; speedup 1.0000x reference)
//
#include <hip/hip_runtime.h>
#include <cstddef>
#include <math.h>

#define BB 64
#define DD 2048
#define HH 2048
#define BD (BB*DD)   // 131072

typedef unsigned short u16;
typedef __attribute__((ext_vector_type(8))) short bf16x8;
typedef __attribute__((ext_vector_type(4))) float f32x4;
typedef __attribute__((ext_vector_type(4))) float f4;

__device__ __forceinline__ u16 f2b(float x) {
    union { float f; unsigned u; } v; v.f = x;
    unsigned r = v.u + 0x7FFFu + ((v.u >> 16) & 1u);
    return (u16)(r >> 16);
}

// ===========================================================================
// full-K (K=2048) 64x64 MFMA GEMM; A bf16 (reg passthrough), W f32
// (reg-staged convert+transpose). 2 LDS buffers, 2-deep register prefetch,
// raw s_barrier (no vmcnt drain) so prefetch loads stay in flight.
// sm layout per buffer: [A0 2048 u16][A1 2048 (NS==2)][W 2048]
// ===========================================================================
template<int NS>
__device__ __forceinline__ void gemm_fk2(
    u16* sm, const u16* __restrict__ A0, const u16* __restrict__ A1,
    const float* __restrict__ W, int nblk, f32x4* acc0, f32x4* acc1)
{
    constexpr int NS1 = NS + 1;
    constexpr int REG = NS1 * 2048;      // u16 per buffer
    const int t = threadIdx.x, w = t >> 6, lane = t & 63;
    const int n0 = nblk * 64;

    // A staging map: thread -> (row am, k-offset ak8); ds_write_b128 linear
    const int am  = t >> 2;              // 0..63
    const int ak8 = (t & 3) * 8;         // 0,8,16,24
    // W staging map: thread -> (k-pair kp, col base c4)
    const int kp = t >> 4;               // 0..15  (rows 2kp, 2kp+1 of chunk)
    const int c4 = (t & 15) * 4;         // 0..60
    // fragment map
    const int lane15 = lane & 15;
    const int k8f = (lane >> 4) * 8;

    const u16* pa0 = A0 + (size_t)am * DD + ak8;
    const u16* pa1 = (NS == 2) ? A1 + (size_t)am * DD + ak8 : pa0;
    const float* pw = W + (size_t)(2 * kp) * DD + n0 + c4;

    struct R { bf16x8 a0; bf16x8 a1; float4 w0, w1; };
    R Ra, Rb;

    auto issue = [&](int it, R& r) {
        r.a0 = *(const bf16x8*)(pa0 + it * 32);
        if constexpr (NS == 2) r.a1 = *(const bf16x8*)(pa1 + it * 32);
        r.w0 = *(const float4*)(pw + (size_t)it * 32 * DD);
        r.w1 = *(const float4*)(pw + (size_t)it * 32 * DD + DD);
    };
    auto store = [&](R& r, u16* buf) {
        *(bf16x8*)(buf + am * 32 + ak8) = r.a0;
        if constexpr (NS == 2)
            *(bf16x8*)(buf + 2048 + am * 32 + ak8) = r.a1;
        u16* wb = buf + (NS1 - 1) * 2048;   // Wls[n][k] : u16 off n*32+k
        unsigned p;
        p = (unsigned)f2b(r.w0.x) | ((unsigned)f2b(r.w1.x) << 16);
        *(unsigned*)(wb + (c4 + 0) * 32 + 2 * kp) = p;
        p = (unsigned)f2b(r.w0.y) | ((unsigned)f2b(r.w1.y) << 16);
        *(unsigned*)(wb + (c4 + 1) * 32 + 2 * kp) = p;
        p = (unsigned)f2b(r.w0.z) | ((unsigned)f2b(r.w1.z) << 16);
        *(unsigned*)(wb + (c4 + 2) * 32 + 2 * kp) = p;
        p = (unsigned)f2b(r.w0.w) | ((unsigned)f2b(r.w1.w) << 16);
        *(unsigned*)(wb + (c4 + 3) * 32 + 2 * kp) = p;
    };
    auto compute = [&](const u16* buf) {
        bf16x8 bfrag = *(const bf16x8*)(buf + (NS1 - 1) * 2048
                                        + (w * 16 + lane15) * 32 + k8f);
#pragma unroll
        for (int mt = 0; mt < 4; ++mt) {
            bf16x8 a = *(const bf16x8*)(buf + (mt * 16 + lane15) * 32 + k8f);
            acc0[mt] = __builtin_amdgcn_mfma_f32_16x16x32_bf16(
                a, bfrag, acc0[mt], 0, 0, 0);
        }
        if constexpr (NS == 2) {
#pragma unroll
            for (int mt = 0; mt < 4; ++mt) {
                bf16x8 a = *(const bf16x8*)(buf + 2048
                                            + (mt * 16 + lane15) * 32 + k8f);
                acc1[mt] = __builtin_amdgcn_mfma_f32_16x16x32_bf16(
                    a, bfrag, acc1[mt], 0, 0, 0);
            }
        }
    };

    u16* b0 = sm;
    u16* b1 = sm + REG;
    issue(0, Ra);
    issue(1, Rb);
#pragma unroll 1
    for (int it2 = 0; it2 < 32; ++it2) {
        // phase A: tile 2*it2 (Ra -> b0)
        store(Ra, b0);
        if (it2 < 31) issue(2 * it2 + 2, Ra);
        asm volatile("s_waitcnt lgkmcnt(0)" ::: "memory");
        __builtin_amdgcn_s_barrier();
        __builtin_amdgcn_sched_barrier(0);
        compute(b0);
        // phase B: tile 2*it2+1 (Rb -> b1)
        store(Rb, b1);
        if (it2 < 31) issue(2 * it2 + 3, Rb);
        asm volatile("s_waitcnt lgkmcnt(0)" ::: "memory");
        __builtin_amdgcn_s_barrier();
        __builtin_amdgcn_sched_barrier(0);
        compute(b1);
    }
}

// ---- dV row-chunk writer: dV[b, chunk*64 .. +64, :] = v ⊗ dK (nt stores)
__device__ __forceinline__ void dv_body(
    const float* __restrict__ v, const float* __restrict__ dK,
    float* __restrict__ dV, int b, int chunk)
{
    int wave = threadIdx.x >> 6;
    int lane = threadIdx.x & 63;

    const f4* dK4 = (const f4*)(dK + ((size_t)b << 11));
    f4 dKr[8];
#pragma unroll
    for (int u = 0; u < 8; ++u) dKr[u] = dK4[u * 64 + lane];

    int row0 = chunk * 64 + wave * 16;
    for (int rr = 0; rr < 16; ++rr) {
        int row = row0 + rr;
        float vr = v[((size_t)b << 11) + row];
        f4* dV4 = (f4*)(dV + (((size_t)((b << 11) | row)) << 11));
#pragma unroll
        for (int u = 0; u < 8; ++u) {
            f4 o = vr * dKr[u];
            __builtin_nontemporal_store(o, &dV4[u * 64 + lane]);
        }
    }
}

// ===========================================================================
// bf16-path kernels
// ===========================================================================

// z f32 -> bf16 (the only pre-pass; 24 MB)
__global__ __launch_bounds__(256) void zconv(
    const float* __restrict__ z, u16* __restrict__ zb)
{
    int i = (blockIdx.x * 256 + threadIdx.x) * 4;
    float4 f = *(const float4*)&z[i];
    union { u16 u[4]; uint2 v; } o;
    o.u[0] = f2b(f.x); o.u[1] = f2b(f.y); o.u[2] = f2b(f.z); o.u[3] = f2b(f.w);
    *(uint2*)&zb[i] = o.v;
}

// mA: 96 blocks = gemm_h | gemm_k | gemm_v (full-K, direct-f32 W, in-block ep)
__global__ __launch_bounds__(256) void mA(
    const u16* __restrict__ zb, const float* __restrict__ W1,
    const float* __restrict__ Wk, const float* __restrict__ Wv,
    const float* __restrict__ b1, const float* __restrict__ bk,
    const float* __restrict__ bv, u16* __restrict__ hb,
    float* __restrict__ dKo, float* __restrict__ vo)
{
    __shared__ u16 sm[2 * 2 * 2048];     // 16 KB
    int blk = blockIdx.x;
    int sel  = blk >> 5;
    int nblk = blk & 31;
    const float* W = (sel == 0) ? W1 : (sel == 1) ? Wk : Wv;

    f32x4 acc[4];
#pragma unroll
    for (int mt = 0; mt < 4; ++mt) acc[mt] = (f32x4){0.f, 0.f, 0.f, 0.f};
    gemm_fk2<1>(sm, zb, zb, W, nblk, acc, nullptr);

    int w = threadIdx.x >> 6, lane = threadIdx.x & 63;
    int col = nblk * 64 + w * 16 + (lane & 15);
    int r4  = (lane >> 4) * 4;
    if (sel == 0) {
        float bb = b1[col];
#pragma unroll
        for (int mt = 0; mt < 4; ++mt)
#pragma unroll
            for (int j = 0; j < 4; ++j)
                hb[(size_t)(mt * 16 + r4 + j) * DD + col] =
                    f2b(tanhf(acc[mt][j] + bb));
    } else if (sel == 1) {
        float bb = bk[col];
#pragma unroll
        for (int mt = 0; mt < 4; ++mt)
#pragma unroll
            for (int j = 0; j < 4; ++j)
                dKo[(size_t)(mt * 16 + r4 + j) * DD + col] =
                    expf(acc[mt][j] + bb);
    } else {
        float bb = bv[col];
#pragma unroll
        for (int mt = 0; mt < 4; ++mt)
#pragma unroll
            for (int j = 0; j < 4; ++j)
                vo[(size_t)(mt * 16 + r4 + j) * DD + col] =
                    acc[mt][j] + bb;
    }
}

// mDZ: [0,32) gemm_dz (A=hb bf16, W2 f32; writes dz f32 + dzb bf16)
//      [32,1056) dv_write b<32
__global__ __launch_bounds__(256) void mDZ(
    const u16* __restrict__ hb, const float* __restrict__ W2,
    const float* __restrict__ b2, float* __restrict__ dz,
    u16* __restrict__ dzb,
    const float* __restrict__ v, const float* __restrict__ dK,
    float* __restrict__ dV)
{
    __shared__ u16 sm[2 * 2 * 2048];     // 16 KB
    int blk = blockIdx.x;
    if (blk < 32) {
        f32x4 acc[4];
#pragma unroll
        for (int mt = 0; mt < 4; ++mt) acc[mt] = (f32x4){0.f, 0.f, 0.f, 0.f};
        gemm_fk2<1>(sm, hb, hb, W2, blk, acc, nullptr);

        int w = threadIdx.x >> 6, lane = threadIdx.x & 63;
        int col = blk * 64 + w * 16 + (lane & 15);
        int r4  = (lane >> 4) * 4;
        float bb = b2[col];
#pragma unroll
        for (int mt = 0; mt < 4; ++mt)
#pragma unroll
            for (int j = 0; j < 4; ++j) {
                float s = acc[mt][j] + bb;
                size_t idx = (size_t)(mt * 16 + r4 + j) * DD + col;
                dz[idx]  = s;
                dzb[idx] = f2b(s);
            }
    } else {
        int r = blk - 32;
        dv_body(v, dK, dV, r >> 5, r & 31);
    }
}

// mQ: [0,32) dual gemm_q (A0=zb, A1=dzb, shared Wq f32 B-frag)
//     [32,1056) dv_write b>=32
__global__ __launch_bounds__(256) void mQ(
    const u16* __restrict__ zb, const u16* __restrict__ dzb,
    const float* __restrict__ Wq, const float* __restrict__ bq,
    float* __restrict__ qo, float* __restrict__ dqo,
    const float* __restrict__ v, const float* __restrict__ dK,
    float* __restrict__ dV)
{
    __shared__ u16 sm[2 * 3 * 2048];     // 24 KB
    int blk = blockIdx.x;
    if (blk < 32) {
        f32x4 az[4], ad[4];
#pragma unroll
        for (int mt = 0; mt < 4; ++mt) {
            az[mt] = (f32x4){0.f, 0.f, 0.f, 0.f};
            ad[mt] = (f32x4){0.f, 0.f, 0.f, 0.f};
        }
        gemm_fk2<2>(sm, zb, dzb, Wq, blk, az, ad);

        int w = threadIdx.x >> 6, lane = threadIdx.x & 63;
        int col = blk * 64 + w * 16 + (lane & 15);
        int r4  = (lane >> 4) * 4;
        float bb = bq[col];
#pragma unroll
        for (int mt = 0; mt < 4; ++mt)
#pragma unroll
            for (int j = 0; j < 4; ++j) {
                float qv = expf(az[mt][j] + bb);
                size_t idx = (size_t)(mt * 16 + r4 + j) * DD + col;
                qo[idx]  = qv;
                dqo[idx] = qv * (ad[mt][j] + bb);
            }
    } else {
        int r = blk - 32;
        dv_body(v, dK, dV, 32 + (r >> 5), r & 31);
    }
}

// a[b] = q . dK ; da[b] = a[b] + dq . K     (one block per batch, L2-hot)
__global__ __launch_bounds__(256) void reduce_a_da(
    const float* __restrict__ q, const float* __restrict__ dK,
    const float* __restrict__ dq, const float* __restrict__ Kin,
    float* __restrict__ a_ws, float* __restrict__ da_out)
{
    int b = blockIdx.x;
    int t = threadIdx.x;
    const float* qb  = q   + (size_t)b * DD;
    const float* dKb = dK  + (size_t)b * DD;
    const float* dqb = dq  + (size_t)b * DD;
    const float* Kb  = Kin + (size_t)b * DD;

    float s1 = 0.f, s2 = 0.f;
    for (int i = t; i < DD; i += 256) {
        s1 = fmaf(qb[i],  dKb[i], s1);
        s2 = fmaf(dqb[i], Kb[i],  s2);
    }
#pragma unroll
    for (int off = 32; off; off >>= 1) {
        s1 += __shfl_down(s1, off);
        s2 += __shfl_down(s2, off);
    }
    __shared__ float r1[4], r2[4];
    if ((t & 63) == 0) { r1[t >> 6] = s1; r2[t >> 6] = s2; }
    __syncthreads();
    if (t == 0) {
        float a  = r1[0] + r1[1] + r1[2] + r1[3];
        float k2 = r2[0] + r2[1] + r2[2] + r2[3];
        a_ws[b]   = a;
        da_out[b] = a + k2;
    }
}

// pure read stream: dc[b,d] = v[b,d]*a[b] + sum_e V[b,d,e]*dq[b,e]
__global__ __launch_bounds__(256) void dc_dot(
    const float* __restrict__ V, const float* __restrict__ v,
    const float* __restrict__ dq, const float* __restrict__ a,
    float* __restrict__ dc)
{
    int b     = blockIdx.x >> 5;
    int chunk = blockIdx.x & 31;
    int wave  = threadIdx.x >> 6;
    int lane  = threadIdx.x & 63;

    const f4* dq4 = (const f4*)(dq + ((size_t)b << 11));
    f4 dqr[8];
#pragma unroll
    for (int u = 0; u < 8; ++u) dqr[u] = dq4[u * 64 + lane];
    float ab = a[b];

    int row0 = chunk * 64 + wave * 16;
    for (int g = 0; g < 4; ++g) {
        float dot[4];
#pragma unroll
        for (int r2i = 0; r2i < 4; ++r2i) {
            int row = row0 + g * 4 + r2i;
            const f4* V4 = (const f4*)(V + (((size_t)((b << 11) | row)) << 11));
            float d = 0.f;
#pragma unroll
            for (int u = 0; u < 8; ++u) {
                f4 Vv = __builtin_nontemporal_load(&V4[u * 64 + lane]);
                d += Vv[0] * dqr[u][0] + Vv[1] * dqr[u][1]
                   + Vv[2] * dqr[u][2] + Vv[3] * dqr[u][3];
            }
            dot[r2i] = d;
        }
#pragma unroll
        for (int r2i = 0; r2i < 4; ++r2i) {
            float d = dot[r2i];
#pragma unroll
            for (int s = 32; s; s >>= 1) d += __shfl_down(d, s);
            if (lane == 0) {
                int row = row0 + g * 4 + r2i;
                dc[((size_t)b << 11) + row] =
                    v[((size_t)b << 11) + row] * ab + d;
            }
        }
    }
}

// ===========================================================================
// f32 fallback GEMM path (used only if d_ws is tiny)
// ===========================================================================
template<int MT>
__device__ __forceinline__ void gemm_body_f32(
    const float* __restrict__ A0, const float* __restrict__ A1,
    const float* __restrict__ W, float* __restrict__ part, int kc)
{
    constexpr int KC = 32;
    constexpr int RT = MT / 16;
    __shared__ float As[KC][MT];
    __shared__ float Ws[KC][64];

    const int t  = threadIdx.x;
    const int n0 = blockIdx.x * 64;
    const int k0 = blockIdx.y * kc;
    const int i  = t >> 4;
    const int j  = t & 15;

    float acc[RT][4];
#pragma unroll
    for (int r = 0; r < RT; ++r)
#pragma unroll
        for (int c = 0; c < 4; ++c) acc[r][c] = 0.f;

    for (int kk0 = 0; kk0 < kc; kk0 += KC) {
        {
            int kk = t >> 3;
            int nn = (t & 7) << 3;
            const float* s = W + (size_t)(k0 + kk0 + kk) * DD + n0 + nn;
            *(float4*)&Ws[kk][nn]     = *(const float4*)s;
            *(float4*)&Ws[kk][nn + 4] = *(const float4*)(s + 4);
        }
        if constexpr (MT == 64) {
            int m  = t & 63;
            int kb = (t >> 6) << 3;
            const float* s = A0 + (size_t)m * DD + k0 + kk0 + kb;
            float4 a0 = *(const float4*)s;
            float4 a1 = *(const float4*)(s + 4);
            As[kb+0][m] = a0.x; As[kb+1][m] = a0.y;
            As[kb+2][m] = a0.z; As[kb+3][m] = a0.w;
            As[kb+4][m] = a1.x; As[kb+5][m] = a1.y;
            As[kb+6][m] = a1.z; As[kb+7][m] = a1.w;
        } else {
            int m  = t & 127;
            int kb = (t >> 7) << 4;
            const float* base = (m < 64) ? (A0 + (size_t)m * DD)
                                         : (A1 + (size_t)(m - 64) * DD);
            const float* s = base + k0 + kk0 + kb;
#pragma unroll
            for (int p = 0; p < 4; ++p) {
                float4 av = *(const float4*)(s + p * 4);
                As[kb+p*4+0][m] = av.x; As[kb+p*4+1][m] = av.y;
                As[kb+p*4+2][m] = av.z; As[kb+p*4+3][m] = av.w;
            }
        }
        __syncthreads();
#pragma unroll
        for (int kk = 0; kk < KC; ++kk) {
            float4 wv = *(float4*)&Ws[kk][j << 2];
#pragma unroll
            for (int rq = 0; rq < RT / 4; ++rq) {
                float4 av = *(float4*)&As[kk][i * RT + rq * 4];
                acc[rq*4+0][0] = fmaf(av.x, wv.x, acc[rq*4+0][0]);
                acc[rq*4+0][1] = fmaf(av.x, wv.y, acc[rq*4+0][1]);
                acc[rq*4+0][2] = fmaf(av.x, wv.z, acc[rq*4+0][2]);
                acc[rq*4+0][3] = fmaf(av.x, wv.w, acc[rq*4+0][3]);
                acc[rq*4+1][0] = fmaf(av.y, wv.x, acc[rq*4+1][0]);
                acc[rq*4+1][1] = fmaf(av.y, wv.y, acc[rq*4+1][1]);
                acc[rq*4+1][2] = fmaf(av.y, wv.z, acc[rq*4+1][2]);
                acc[rq*4+1][3] = fmaf(av.y, wv.w, acc[rq*4+1][3]);
                acc[rq*4+2][0] = fmaf(av.z, wv.x, acc[rq*4+2][0]);
                acc[rq*4+2][1] = fmaf(av.z, wv.y, acc[rq*4+2][1]);
                acc[rq*4+2][2] = fmaf(av.z, wv.z, acc[rq*4+2][2]);
                acc[rq*4+2][3] = fmaf(av.z, wv.w, acc[rq*4+2][3]);
                acc[rq*4+3][0] = fmaf(av.w, wv.x, acc[rq*4+3][0]);
                acc[rq*4+3][1] = fmaf(av.w, wv.y, acc[rq*4+3][1]);
                acc[rq*4+3][2] = fmaf(av.w, wv.z, acc[rq*4+3][2]);
                acc[rq*4+3][3] = fmaf(av.w, wv.w, acc[rq*4+3][3]);
            }
        }
        __syncthreads();
    }

    float* P = part + (size_t)blockIdx.y * MT * DD + n0 + (j << 2);
#pragma unroll
    for (int r = 0; r < RT; ++r)
        *(float4*)&P[(size_t)(i * RT + r) * DD] =
            make_float4(acc[r][0], acc[r][1], acc[r][2], acc[r][3]);
}

__global__ __launch_bounds__(256) void gemm64(
    const float* __restrict__ A, const float* __restrict__ W,
    float* __restrict__ part, int kc)
{ gemm_body_f32<64>(A, A, W, part, kc); }

__global__ __launch_bounds__(256) void gemm64_z2(
    const float* __restrict__ A,
    const float* __restrict__ W0, const float* __restrict__ W1,
    float* __restrict__ p0, float* __restrict__ p1, int kc)
{
    const float* W = blockIdx.z ? W1 : W0;
    float*       P = blockIdx.z ? p1 : p0;
    gemm_body_f32<64>(A, A, W, P, kc);
}

__global__ __launch_bounds__(256) void gemm128(
    const float* __restrict__ A0, const float* __restrict__ A1,
    const float* __restrict__ W, float* __restrict__ part, int kc)
{ gemm_body_f32<128>(A0, A1, W, part, kc); }

__global__ __launch_bounds__(256) void epilogue_f32(
    const float* __restrict__ part, const float* __restrict__ bias,
    float* __restrict__ out, int act, int KS)
{
    int i = blockIdx.x * 256 + threadIdx.x;
    float s = bias[i & (DD - 1)];
    for (int ks = 0; ks < KS; ++ks) s += part[(size_t)ks * BD + i];
    if (act == 1) s = tanhf(s);
    out[i] = s;
}

__global__ __launch_bounds__(256) void ep_kv_f32(
    const float* __restrict__ pk, const float* __restrict__ pv,
    const float* __restrict__ bk, const float* __restrict__ bv,
    float* __restrict__ dKo, float* __restrict__ vo, int KS)
{
    int i = blockIdx.x * 256 + threadIdx.x;
    int d = i & (DD - 1);
    float sk = 0.f, sv = 0.f;
    for (int ks = 0; ks < KS; ++ks) {
        sk += pk[(size_t)ks * BD + i];
        sv += pv[(size_t)ks * BD + i];
    }
    dKo[i] = expf(sk + bk[d]);
    vo[i]  = sv + bv[d];
}

__global__ __launch_bounds__(256) void ep_q_dq_f32(
    const float* __restrict__ pq, const float* __restrict__ bq,
    float* __restrict__ qo, float* __restrict__ dqo, int KS)
{
    int i = blockIdx.x * 256 + threadIdx.x;
    int b = i >> 11, d = i & (DD - 1);
    float sq = 0.f, sd = 0.f;
    for (int ks = 0; ks < KS; ++ks) {
        const float* P = pq + (size_t)ks * (128 * DD);
        sq += P[(size_t)b * DD + d];
        sd += P[(size_t)(b + 64) * DD + d];
    }
    float bb = bq[d];
    float qv = expf(sq + bb);
    qo[i]  = qv;
    dqo[i] = qv * (sd + bb);
}

__global__ __launch_bounds__(256) void dv_write_full(
    const float* __restrict__ v, const float* __restrict__ dK,
    float* __restrict__ dV)
{
    dv_body(v, dK, dV, blockIdx.x >> 5, blockIdx.x & 31);
}

// ===========================================================================
extern "C" void kernel_launch(void* const* d_in, const int* in_sizes, int n_in,
                              void* d_out, int out_size, void* d_ws, size_t ws_size,
                              hipStream_t stream)
{
    const float* z   = (const float*)d_in[1];
    const float* Kin = (const float*)d_in[2];
    const float* Vin = (const float*)d_in[3];
    const float* Wq  = (const float*)d_in[4];
    const float* bq  = (const float*)d_in[5];
    const float* Wk  = (const float*)d_in[6];
    const float* bk  = (const float*)d_in[7];
    const float* Wv  = (const float*)d_in[8];
    const float* bv  = (const float*)d_in[9];
    const float* W1  = (const float*)d_in[10];
    const float* b1  = (const float*)d_in[11];
    const float* W2  = (const float*)d_in[12];
    const float* b2  = (const float*)d_in[13];

    float* out   = (float*)d_out;
    float* o_dz  = out;
    float* o_da  = out + BD;
    float* o_dc  = out + BD + BB;
    float* o_dK  = out + 2 * BD + BB;
    float* o_dV  = out + 3 * BD + BB;

    float* ws    = (float*)d_ws;
    float* ws_v  = ws;
    float* ws_q  = ws + BD;
    float* ws_dq = ws + 2 * BD;
    float* ws_a  = ws + 3 * BD;          // 64
    float* ws_h  = ws + 3 * BD + 64;     // fallback only
    u16*   zb    = (u16*)(ws + 4 * BD + 64);
    u16*   hb    = zb + BD;
    u16*   dzb   = hb + BD;

    // bf16 path needs: 4*BD+64 floats + 3*BD u16
    const size_t pre_fl = 4ull * BD + 64 + (3ull * BD + 1) / 2;

    dim3 blk(256);

    if (pre_fl * 4ull <= ws_size) {
        // -------- bf16 MFMA path: direct-f32 weights, no transpose pass ----
        // 0) z -> bf16 (24 MB, ~4 us)
        zconv<<<dim3(BD / 1024), blk, 0, stream>>>(z, zb);

        // 1) gemm_h | gemm_k | gemm_v (full-K, in-block epilogue)
        mA<<<dim3(96), blk, 0, stream>>>(
            zb, W1, Wk, Wv, b1, bk, bv, hb, o_dK, ws_v);

        // 2) gemm_dz (+dzb) ∥ dv_write b<32
        mDZ<<<dim3(32 + 1024), blk, 0, stream>>>(
            hb, W2, b2, o_dz, dzb, ws_v, o_dK, o_dV);

        // 3) dual gemm_q ∥ dv_write b>=32
        mQ<<<dim3(32 + 1024), blk, 0, stream>>>(
            zb, dzb, Wq, bq, ws_q, ws_dq, ws_v, o_dK, o_dV);
    } else {
        // ------------------- f32 fallback path -------------------
        float* pool = ws + 4 * BD + 64;
        int KSf = 16;
        while (KSf > 1 &&
               ((size_t)(4 * BD + 64) + 2ull * KSf * BD) * 4ull > ws_size)
            KSf >>= 1;
        int kc = DD / KSf;
        float* p0 = pool;
        float* p1 = pool + (size_t)KSf * BD;

        dim3 gG(DD / 64, KSf);
        dim3 gG2(DD / 64, KSf, 2);
        dim3 gE(BD / 256);

        gemm64<<<gG, blk, 0, stream>>>(z, W1, p0, kc);
        epilogue_f32<<<gE, blk, 0, stream>>>(p0, b1, ws_h, 1, KSf);

        gemm64<<<gG, blk, 0, stream>>>(ws_h, W2, p0, kc);
        epilogue_f32<<<gE, blk, 0, stream>>>(p0, b2, o_dz, 0, KSf);

        gemm64_z2<<<gG2, blk, 0, stream>>>(z, Wk, Wv, p0, p1, kc);
        ep_kv_f32<<<gE, blk, 0, stream>>>(p0, p1, bk, bv, o_dK, ws_v, KSf);

        dv_write_full<<<dim3(BB * 32), blk, 0, stream>>>(ws_v, o_dK, o_dV);

        gemm128<<<gG, blk, 0, stream>>>(z, o_dz, Wq, p0, kc);
        ep_q_dq_f32<<<gE, blk, 0, stream>>>(p0, bq, ws_q, ws_dq, KSf);
    }

    // 4) a = q . dK ; da = a + dq . K   (tiny, L2-hot inputs)
    reduce_a_da<<<dim3(BB), blk, 0, stream>>>(ws_q, o_dK, ws_dq, Kin, ws_a, o_da);

    // 5) dc = v*a + V @ dq  — pure nt-read stream
    dc_dot<<<dim3(BB * 32), blk, 0, stream>>>(Vin, ws_v, ws_dq, ws_a, o_dc);
}

// Round 10
// 415.475 us; speedup vs baseline: 1.0382x; 1.0382x over previous
//
#include <hip/hip_runtime.h>
#include <cstddef>
#include <math.h>

#define BB 64
#define DD 2048
#define HH 2048
#define BD (BB*DD)   // 131072
#define WN (2048*2048)

typedef unsigned short u16;
typedef __attribute__((ext_vector_type(8))) short bf16x8;
typedef __attribute__((ext_vector_type(4))) float f32x4;
typedef __attribute__((ext_vector_type(4))) float f4;

__device__ __forceinline__ u16 f2b(float x) {
    union { float f; unsigned u; } v; v.f = x;
    unsigned r = v.u + 0x7FFFu + ((v.u >> 16) & 1u);
    return (u16)(r >> 16);
}

__device__ __forceinline__ void gload16(const void* g, void* l) {
    __builtin_amdgcn_global_load_lds(
        (__attribute__((address_space(1))) void*)g,
        (__attribute__((address_space(3))) void*)l, 16, 0, 0);
}

// ===========================================================================
// shared device bodies
// ===========================================================================

// weight tile f32[k][n] -> bf16 T[n][k]; sm >= 64*66 u16
__device__ __forceinline__ void wconv_tile(
    u16* sm, const float* __restrict__ W, u16* __restrict__ T,
    int kb, int nb)
{
    int t = threadIdx.x;
    int k0 = kb * 64, n0 = nb * 64;
    {
        int r = t >> 2, c0 = (t & 3) * 16;
        const float* src = W + (size_t)(k0 + r) * DD + n0 + c0;
#pragma unroll
        for (int q = 0; q < 4; ++q) {
            float4 f = *(const float4*)(src + q * 4);
            sm[r * 66 + c0 + q*4 + 0] = f2b(f.x);
            sm[r * 66 + c0 + q*4 + 1] = f2b(f.y);
            sm[r * 66 + c0 + q*4 + 2] = f2b(f.z);
            sm[r * 66 + c0 + q*4 + 3] = f2b(f.w);
        }
    }
    __syncthreads();
    {
        int rn = t >> 2, ck = (t & 3) * 16;
        u16 o[16];
#pragma unroll
        for (int j = 0; j < 16; ++j) o[j] = sm[(ck + j) * 66 + rn];
        u16* dst = T + (size_t)(n0 + rn) * DD + k0 + ck;
        *(bf16x8*)dst       = *(bf16x8*)&o[0];
        *(bf16x8*)(dst + 8) = *(bf16x8*)&o[8];
    }
}

// ---- full-K (K=2048) 64x64 MFMA GEMM, 4-buffer 3-ahead gload_lds pipeline.
// NS = # A-streams (1 or 2). sm: 4 * (NS+1) * 2048 u16.
// Counted vmcnt + raw s_barrier: prefetch loads stay in flight across barriers.
template<int NS>
__device__ __forceinline__ void gemm_fullk(
    u16* sm, const u16* __restrict__ A0, const u16* __restrict__ A1,
    const u16* __restrict__ Wt, int nblk, f32x4* acc0, f32x4* acc1)
{
    constexpr int NS1 = NS + 1;
    constexpr int REG = NS1 * 2048;      // u16 per buffer
    const int t = threadIdx.x, w = t >> 6, lane = t & 63;
    const int n0 = nblk * 64;
    const int srow = lane >> 2;          // 0..15
    const int sk   = (lane & 3) * 8;     // u16 offset, 16B chunks

    const u16* gA0 = A0 + (size_t)(w * 16 + srow) * DD + sk;
    const u16* gA1 = (NS == 2) ? A1 + (size_t)(w * 16 + srow) * DD + sk : A0;
    const u16* gW  = Wt + (size_t)(n0 + w * 16 + srow) * DD + sk;
    const int woff = w * 512;

    const int lane15 = lane & 15;
    const int k8 = (lane >> 4) * 8;

    auto stage = [&](int it, int buf) {
        u16* base = sm + buf * REG;
        gload16(gA0 + it * 32, base + woff);
        if constexpr (NS == 2) gload16(gA1 + it * 32, base + 2048 + woff);
        gload16(gW + it * 32, base + (NS1 - 1) * 2048 + woff);
    };

    constexpr int nt = DD / 32;          // 64
    stage(0, 0);
    stage(1, 1);
    stage(2, 2);
    for (int it = 0; it < nt; ++it) {
        const int cur = it & 3;
        if (it + 3 < nt) {
            stage(it + 3, (it + 3) & 3);
            if constexpr (NS == 1) asm volatile("s_waitcnt vmcnt(6)" ::: "memory");
            else                   asm volatile("s_waitcnt vmcnt(9)" ::: "memory");
        } else if (it + 2 < nt) {
            if constexpr (NS == 1) asm volatile("s_waitcnt vmcnt(4)" ::: "memory");
            else                   asm volatile("s_waitcnt vmcnt(6)" ::: "memory");
        } else if (it + 1 < nt) {
            if constexpr (NS == 1) asm volatile("s_waitcnt vmcnt(2)" ::: "memory");
            else                   asm volatile("s_waitcnt vmcnt(3)" ::: "memory");
        } else {
            asm volatile("s_waitcnt vmcnt(0)" ::: "memory");
        }
        __builtin_amdgcn_s_barrier();

        const u16* base = sm + cur * REG;
        bf16x8 bfrag = *(const bf16x8*)&base[(NS1-1)*2048 + (w*16 + lane15)*32 + k8];
#pragma unroll
        for (int mt = 0; mt < 4; ++mt) {
            bf16x8 a0 = *(const bf16x8*)&base[(mt*16 + lane15)*32 + k8];
            acc0[mt] = __builtin_amdgcn_mfma_f32_16x16x32_bf16(a0, bfrag, acc0[mt], 0, 0, 0);
        }
        if constexpr (NS == 2) {
#pragma unroll
            for (int mt = 0; mt < 4; ++mt) {
                bf16x8 a1 = *(const bf16x8*)&base[2048 + (mt*16 + lane15)*32 + k8];
                acc1[mt] = __builtin_amdgcn_mfma_f32_16x16x32_bf16(a1, bfrag, acc1[mt], 0, 0, 0);
            }
        }
        __builtin_amdgcn_s_barrier();
    }
}

// ---- dV row-chunk writer: dV[b, chunk*64 .. +64, :] = v ⊗ dK (nt stores)
__device__ __forceinline__ void dv_body(
    const float* __restrict__ v, const float* __restrict__ dK,
    float* __restrict__ dV, int b, int chunk)
{
    int wave = threadIdx.x >> 6;
    int lane = threadIdx.x & 63;

    const f4* dK4 = (const f4*)(dK + ((size_t)b << 11));
    f4 dKr[8];
#pragma unroll
    for (int u = 0; u < 8; ++u) dKr[u] = dK4[u * 64 + lane];

    int row0 = chunk * 64 + wave * 16;
    for (int rr = 0; rr < 16; ++rr) {
        int row = row0 + rr;
        float vr = v[((size_t)b << 11) + row];
        f4* dV4 = (f4*)(dV + (((size_t)((b << 11) | row)) << 11));
#pragma unroll
        for (int u = 0; u < 8; ++u) {
            f4 o = vr * dKr[u];
            __builtin_nontemporal_store(o, &dV4[u * 64 + lane]);
        }
    }
}

// ===========================================================================
// bf16-path kernels
// ===========================================================================

// k_pre: convert W1, Wk, Wv (z=0..2) and z->bf16 (z=3)
__global__ __launch_bounds__(256) void wconv1(
    const float* __restrict__ W1, const float* __restrict__ Wk,
    const float* __restrict__ Wv, u16* __restrict__ W1t,
    u16* __restrict__ Wkt, u16* __restrict__ Wvt,
    const float* __restrict__ z, u16* __restrict__ zb)
{
    __shared__ u16 sm[64 * 66];
    int t = threadIdx.x;
    if (blockIdx.z == 3) {
        if (blockIdx.y != 0 || blockIdx.x >= 32) return;
        int i0 = blockIdx.x * 4096 + t * 16;
        u16 o[16];
#pragma unroll
        for (int q = 0; q < 4; ++q) {
            float4 f = *(const float4*)&z[i0 + q * 4];
            o[q*4+0] = f2b(f.x); o[q*4+1] = f2b(f.y);
            o[q*4+2] = f2b(f.z); o[q*4+3] = f2b(f.w);
        }
        *(bf16x8*)&zb[i0]     = *(bf16x8*)&o[0];
        *(bf16x8*)&zb[i0 + 8] = *(bf16x8*)&o[8];
        return;
    }
    const float* W = (blockIdx.z == 0) ? W1 : (blockIdx.z == 1) ? Wk : Wv;
    u16* T = (blockIdx.z == 0) ? W1t : (blockIdx.z == 1) ? Wkt : Wvt;
    wconv_tile(sm, W, T, blockIdx.x, blockIdx.y);
}

// mA: [0,32) gemm_h | [32,64) gemm_k | [64,96) gemm_v | [96,2144) wconv W2,Wq
__global__ __launch_bounds__(256) void mA(
    const u16* __restrict__ zb, const u16* __restrict__ W1t,
    const u16* __restrict__ Wkt, const u16* __restrict__ Wvt,
    const float* __restrict__ b1, const float* __restrict__ bk,
    const float* __restrict__ bv, u16* __restrict__ hb,
    float* __restrict__ dKo, float* __restrict__ vo,
    const float* __restrict__ W2, const float* __restrict__ Wq,
    u16* __restrict__ W2t, u16* __restrict__ Wqt)
{
    __shared__ u16 sm[4 * 4096];         // 32 KB
    int blk = blockIdx.x;
    if (blk < 96) {
        int sel  = blk >> 5;
        int nblk = blk & 31;
        const u16* Wt = (sel == 0) ? W1t : (sel == 1) ? Wkt : Wvt;
        f32x4 acc[4];
#pragma unroll
        for (int mt = 0; mt < 4; ++mt) acc[mt] = (f32x4){0.f,0.f,0.f,0.f};
        gemm_fullk<1>(sm, zb, zb, Wt, nblk, acc, nullptr);

        int w = threadIdx.x >> 6, lane = threadIdx.x & 63;
        int col = nblk * 64 + w * 16 + (lane & 15);
        int r4  = (lane >> 4) * 4;
        if (sel == 0) {
            float bb = b1[col];
#pragma unroll
            for (int mt = 0; mt < 4; ++mt)
#pragma unroll
                for (int j = 0; j < 4; ++j)
                    hb[(size_t)(mt*16 + r4 + j) * DD + col] =
                        f2b(tanhf(acc[mt][j] + bb));
        } else if (sel == 1) {
            float bb = bk[col];
#pragma unroll
            for (int mt = 0; mt < 4; ++mt)
#pragma unroll
                for (int j = 0; j < 4; ++j)
                    dKo[(size_t)(mt*16 + r4 + j) * DD + col] =
                        expf(acc[mt][j] + bb);
        } else {
            float bb = bv[col];
#pragma unroll
            for (int mt = 0; mt < 4; ++mt)
#pragma unroll
                for (int j = 0; j < 4; ++j)
                    vo[(size_t)(mt*16 + r4 + j) * DD + col] =
                        acc[mt][j] + bb;
        }
    } else {
        int r = blk - 96;                // 0..2047
        const float* W = (r < 1024) ? W2 : Wq;
        u16* T         = (r < 1024) ? W2t : Wqt;
        int rr = r & 1023;
        wconv_tile(sm, W, T, rr & 31, rr >> 5);
    }
}

// mDZ: [0,32) gemm_dz (full-K, writes dz f32 + dzb bf16) | [32,1056) dv b<32
__global__ __launch_bounds__(256) void mDZ(
    const u16* __restrict__ hb, const u16* __restrict__ W2t,
    const float* __restrict__ b2, float* __restrict__ dz,
    u16* __restrict__ dzb,
    const float* __restrict__ v, const float* __restrict__ dK,
    float* __restrict__ dV)
{
    __shared__ u16 sm[4 * 4096];         // 32 KB
    int blk = blockIdx.x;
    if (blk < 32) {
        f32x4 acc[4];
#pragma unroll
        for (int mt = 0; mt < 4; ++mt) acc[mt] = (f32x4){0.f,0.f,0.f,0.f};
        gemm_fullk<1>(sm, hb, hb, W2t, blk, acc, nullptr);

        int w = threadIdx.x >> 6, lane = threadIdx.x & 63;
        int col = blk * 64 + w * 16 + (lane & 15);
        int r4  = (lane >> 4) * 4;
        float bb = b2[col];
#pragma unroll
        for (int mt = 0; mt < 4; ++mt)
#pragma unroll
            for (int j = 0; j < 4; ++j) {
                float s = acc[mt][j] + bb;
                size_t idx = (size_t)(mt*16 + r4 + j) * DD + col;
                dz[idx]  = s;
                dzb[idx] = f2b(s);
            }
    } else {
        int r = blk - 32;
        dv_body(v, dK, dV, r >> 5, r & 31);
    }
}

// mQ: [0,32) dual gemm_q (z@Wq and dz@Wq share B-frag) | [32,1056) dv b>=32
__global__ __launch_bounds__(256) void mQ(
    const u16* __restrict__ zb, const u16* __restrict__ dzb,
    const u16* __restrict__ Wqt, const float* __restrict__ bq,
    float* __restrict__ qo, float* __restrict__ dqo,
    const float* __restrict__ v, const float* __restrict__ dK,
    float* __restrict__ dV)
{
    __shared__ u16 sm[4 * 6144];         // 48 KB
    int blk = blockIdx.x;
    if (blk < 32) {
        f32x4 az[4], ad[4];
#pragma unroll
        for (int mt = 0; mt < 4; ++mt) {
            az[mt] = (f32x4){0.f,0.f,0.f,0.f};
            ad[mt] = (f32x4){0.f,0.f,0.f,0.f};
        }
        gemm_fullk<2>(sm, zb, dzb, Wqt, blk, az, ad);

        int w = threadIdx.x >> 6, lane = threadIdx.x & 63;
        int col = blk * 64 + w * 16 + (lane & 15);
        int r4  = (lane >> 4) * 4;
        float bb = bq[col];
#pragma unroll
        for (int mt = 0; mt < 4; ++mt)
#pragma unroll
            for (int j = 0; j < 4; ++j) {
                float qv = expf(az[mt][j] + bb);
                size_t idx = (size_t)(mt*16 + r4 + j) * DD + col;
                qo[idx]  = qv;
                dqo[idx] = qv * (ad[mt][j] + bb);
            }
    } else {
        int r = blk - 32;
        dv_body(v, dK, dV, 32 + (r >> 5), r & 31);
    }
}

// a[b] = q . dK ; da[b] = a[b] + dq . K     (one block per batch, L2-hot)
__global__ __launch_bounds__(256) void reduce_a_da(
    const float* __restrict__ q, const float* __restrict__ dK,
    const float* __restrict__ dq, const float* __restrict__ Kin,
    float* __restrict__ a_ws, float* __restrict__ da_out)
{
    int b = blockIdx.x;
    int t = threadIdx.x;
    const float* qb  = q   + (size_t)b * DD;
    const float* dKb = dK  + (size_t)b * DD;
    const float* dqb = dq  + (size_t)b * DD;
    const float* Kb  = Kin + (size_t)b * DD;

    float s1 = 0.f, s2 = 0.f;
    for (int i = t; i < DD; i += 256) {
        s1 = fmaf(qb[i],  dKb[i], s1);
        s2 = fmaf(dqb[i], Kb[i],  s2);
    }
#pragma unroll
    for (int off = 32; off; off >>= 1) {
        s1 += __shfl_down(s1, off);
        s2 += __shfl_down(s2, off);
    }
    __shared__ float r1[4], r2[4];
    if ((t & 63) == 0) { r1[t >> 6] = s1; r2[t >> 6] = s2; }
    __syncthreads();
    if (t == 0) {
        float a  = r1[0] + r1[1] + r1[2] + r1[3];
        float k2 = r2[0] + r2[1] + r2[2] + r2[3];
        a_ws[b]   = a;
        da_out[b] = a + k2;
    }
}

// pure read stream: dc[b,d] = v[b,d]*a[b] + sum_e V[b,d,e]*dq[b,e]
__global__ __launch_bounds__(256) void dc_dot(
    const float* __restrict__ V, const float* __restrict__ v,
    const float* __restrict__ dq, const float* __restrict__ a,
    float* __restrict__ dc)
{
    int b     = blockIdx.x >> 5;
    int chunk = blockIdx.x & 31;
    int wave  = threadIdx.x >> 6;
    int lane  = threadIdx.x & 63;

    const f4* dq4 = (const f4*)(dq + ((size_t)b << 11));
    f4 dqr[8];
#pragma unroll
    for (int u = 0; u < 8; ++u) dqr[u] = dq4[u * 64 + lane];
    float ab = a[b];

    int row0 = chunk * 64 + wave * 16;
    for (int g = 0; g < 4; ++g) {
        float dot[4];
#pragma unroll
        for (int r2i = 0; r2i < 4; ++r2i) {
            int row = row0 + g * 4 + r2i;
            const f4* V4 = (const f4*)(V + (((size_t)((b << 11) | row)) << 11));
            float d = 0.f;
#pragma unroll
            for (int u = 0; u < 8; ++u) {
                f4 Vv = __builtin_nontemporal_load(&V4[u * 64 + lane]);
                d += Vv[0] * dqr[u][0] + Vv[1] * dqr[u][1]
                   + Vv[2] * dqr[u][2] + Vv[3] * dqr[u][3];
            }
            dot[r2i] = d;
        }
#pragma unroll
        for (int r2i = 0; r2i < 4; ++r2i) {
            float d = dot[r2i];
#pragma unroll
            for (int s = 32; s; s >>= 1) d += __shfl_down(d, s);
            if (lane == 0) {
                int row = row0 + g * 4 + r2i;
                dc[((size_t)b << 11) + row] =
                    v[((size_t)b << 11) + row] * ab + d;
            }
        }
    }
}

// ===========================================================================
// f32 fallback GEMM path (used only if d_ws is small)
// ===========================================================================
template<int MT>
__device__ __forceinline__ void gemm_body_f32(
    const float* __restrict__ A0, const float* __restrict__ A1,
    const float* __restrict__ W, float* __restrict__ part, int kc)
{
    constexpr int KC = 32;
    constexpr int RT = MT / 16;
    __shared__ float As[KC][MT];
    __shared__ float Ws[KC][64];

    const int t  = threadIdx.x;
    const int n0 = blockIdx.x * 64;
    const int k0 = blockIdx.y * kc;
    const int i  = t >> 4;
    const int j  = t & 15;

    float acc[RT][4];
#pragma unroll
    for (int r = 0; r < RT; ++r)
#pragma unroll
        for (int c = 0; c < 4; ++c) acc[r][c] = 0.f;

    for (int kk0 = 0; kk0 < kc; kk0 += KC) {
        {
            int kk = t >> 3;
            int nn = (t & 7) << 3;
            const float* s = W + (size_t)(k0 + kk0 + kk) * DD + n0 + nn;
            *(float4*)&Ws[kk][nn]     = *(const float4*)s;
            *(float4*)&Ws[kk][nn + 4] = *(const float4*)(s + 4);
        }
        if constexpr (MT == 64) {
            int m  = t & 63;
            int kb = (t >> 6) << 3;
            const float* s = A0 + (size_t)m * DD + k0 + kk0 + kb;
            float4 a0 = *(const float4*)s;
            float4 a1 = *(const float4*)(s + 4);
            As[kb+0][m] = a0.x; As[kb+1][m] = a0.y;
            As[kb+2][m] = a0.z; As[kb+3][m] = a0.w;
            As[kb+4][m] = a1.x; As[kb+5][m] = a1.y;
            As[kb+6][m] = a1.z; As[kb+7][m] = a1.w;
        } else {
            int m  = t & 127;
            int kb = (t >> 7) << 4;
            const float* base = (m < 64) ? (A0 + (size_t)m * DD)
                                         : (A1 + (size_t)(m - 64) * DD);
            const float* s = base + k0 + kk0 + kb;
#pragma unroll
            for (int p = 0; p < 4; ++p) {
                float4 av = *(const float4*)(s + p * 4);
                As[kb+p*4+0][m] = av.x; As[kb+p*4+1][m] = av.y;
                As[kb+p*4+2][m] = av.z; As[kb+p*4+3][m] = av.w;
            }
        }
        __syncthreads();
#pragma unroll
        for (int kk = 0; kk < KC; ++kk) {
            float4 wv = *(float4*)&Ws[kk][j << 2];
#pragma unroll
            for (int rq = 0; rq < RT / 4; ++rq) {
                float4 av = *(float4*)&As[kk][i * RT + rq * 4];
                acc[rq*4+0][0] = fmaf(av.x, wv.x, acc[rq*4+0][0]);
                acc[rq*4+0][1] = fmaf(av.x, wv.y, acc[rq*4+0][1]);
                acc[rq*4+0][2] = fmaf(av.x, wv.z, acc[rq*4+0][2]);
                acc[rq*4+0][3] = fmaf(av.x, wv.w, acc[rq*4+0][3]);
                acc[rq*4+1][0] = fmaf(av.y, wv.x, acc[rq*4+1][0]);
                acc[rq*4+1][1] = fmaf(av.y, wv.y, acc[rq*4+1][1]);
                acc[rq*4+1][2] = fmaf(av.y, wv.z, acc[rq*4+1][2]);
                acc[rq*4+1][3] = fmaf(av.y, wv.w, acc[rq*4+1][3]);
                acc[rq*4+2][0] = fmaf(av.z, wv.x, acc[rq*4+2][0]);
                acc[rq*4+2][1] = fmaf(av.z, wv.y, acc[rq*4+2][1]);
                acc[rq*4+2][2] = fmaf(av.z, wv.z, acc[rq*4+2][2]);
                acc[rq*4+2][3] = fmaf(av.z, wv.w, acc[rq*4+2][3]);
                acc[rq*4+3][0] = fmaf(av.w, wv.x, acc[rq*4+3][0]);
                acc[rq*4+3][1] = fmaf(av.w, wv.y, acc[rq*4+3][1]);
                acc[rq*4+3][2] = fmaf(av.w, wv.z, acc[rq*4+3][2]);
                acc[rq*4+3][3] = fmaf(av.w, wv.w, acc[rq*4+3][3]);
            }
        }
        __syncthreads();
    }

    float* P = part + (size_t)blockIdx.y * MT * DD + n0 + (j << 2);
#pragma unroll
    for (int r = 0; r < RT; ++r)
        *(float4*)&P[(size_t)(i * RT + r) * DD] =
            make_float4(acc[r][0], acc[r][1], acc[r][2], acc[r][3]);
}

__global__ __launch_bounds__(256) void gemm64(
    const float* __restrict__ A, const float* __restrict__ W,
    float* __restrict__ part, int kc)
{ gemm_body_f32<64>(A, A, W, part, kc); }

__global__ __launch_bounds__(256) void gemm64_z2(
    const float* __restrict__ A,
    const float* __restrict__ W0, const float* __restrict__ W1,
    float* __restrict__ p0, float* __restrict__ p1, int kc)
{
    const float* W = blockIdx.z ? W1 : W0;
    float*       P = blockIdx.z ? p1 : p0;
    gemm_body_f32<64>(A, A, W, P, kc);
}

__global__ __launch_bounds__(256) void gemm128(
    const float* __restrict__ A0, const float* __restrict__ A1,
    const float* __restrict__ W, float* __restrict__ part, int kc)
{ gemm_body_f32<128>(A0, A1, W, part, kc); }

__global__ __launch_bounds__(256) void epilogue_f32(
    const float* __restrict__ part, const float* __restrict__ bias,
    float* __restrict__ out, int act, int KS)
{
    int i = blockIdx.x * 256 + threadIdx.x;
    float s = bias[i & (DD - 1)];
    for (int ks = 0; ks < KS; ++ks) s += part[(size_t)ks * BD + i];
    if (act == 1) s = tanhf(s);
    out[i] = s;
}

__global__ __launch_bounds__(256) void ep_kv_f32(
    const float* __restrict__ pk, const float* __restrict__ pv,
    const float* __restrict__ bk, const float* __restrict__ bv,
    float* __restrict__ dKo, float* __restrict__ vo, int KS)
{
    int i = blockIdx.x * 256 + threadIdx.x;
    int d = i & (DD - 1);
    float sk = 0.f, sv = 0.f;
    for (int ks = 0; ks < KS; ++ks) {
        sk += pk[(size_t)ks * BD + i];
        sv += pv[(size_t)ks * BD + i];
    }
    dKo[i] = expf(sk + bk[d]);
    vo[i]  = sv + bv[d];
}

__global__ __launch_bounds__(256) void ep_q_dq_f32(
    const float* __restrict__ pq, const float* __restrict__ bq,
    float* __restrict__ qo, float* __restrict__ dqo, int KS)
{
    int i = blockIdx.x * 256 + threadIdx.x;
    int b = i >> 11, d = i & (DD - 1);
    float sq = 0.f, sd = 0.f;
    for (int ks = 0; ks < KS; ++ks) {
        const float* P = pq + (size_t)ks * (128 * DD);
        sq += P[(size_t)b * DD + d];
        sd += P[(size_t)(b + 64) * DD + d];
    }
    float bb = bq[d];
    float qv = expf(sq + bb);
    qo[i]  = qv;
    dqo[i] = qv * (sd + bb);
}

__global__ __launch_bounds__(256) void dv_write_full(
    const float* __restrict__ v, const float* __restrict__ dK,
    float* __restrict__ dV)
{
    dv_body(v, dK, dV, blockIdx.x >> 5, blockIdx.x & 31);
}

// ===========================================================================
extern "C" void kernel_launch(void* const* d_in, const int* in_sizes, int n_in,
                              void* d_out, int out_size, void* d_ws, size_t ws_size,
                              hipStream_t stream)
{
    const float* z   = (const float*)d_in[1];
    const float* Kin = (const float*)d_in[2];
    const float* Vin = (const float*)d_in[3];
    const float* Wq  = (const float*)d_in[4];
    const float* bq  = (const float*)d_in[5];
    const float* Wk  = (const float*)d_in[6];
    const float* bk  = (const float*)d_in[7];
    const float* Wv  = (const float*)d_in[8];
    const float* bv  = (const float*)d_in[9];
    const float* W1  = (const float*)d_in[10];
    const float* b1  = (const float*)d_in[11];
    const float* W2  = (const float*)d_in[12];
    const float* b2  = (const float*)d_in[13];

    float* out   = (float*)d_out;
    float* o_dz  = out;
    float* o_da  = out + BD;
    float* o_dc  = out + BD + BB;
    float* o_dK  = out + 2 * BD + BB;
    float* o_dV  = out + 3 * BD + BB;

    float* ws    = (float*)d_ws;
    float* ws_v  = ws;
    float* ws_q  = ws + BD;
    float* ws_dq = ws + 2 * BD;
    float* ws_a  = ws + 3 * BD;          // 64
    float* ws_h  = ws + 3 * BD + 64;     // fallback only
    u16*   zb    = (u16*)(ws + 4 * BD + 64);
    u16*   hb    = zb + BD;
    u16*   dzb   = hb + BD;
    u16*   wt    = dzb + BD;             // 5 * WN u16

    // bf16 path floats needed
    const size_t pre_fl = 4ull * BD + 64 + (3ull * BD + 5ull * WN) / 2;

    dim3 blk(256);

    if (pre_fl * 4ull <= ws_size) {
        // ------------------- bf16 MFMA path: 6 dispatches -------------------
        u16* W1t = wt;
        u16* W2t = wt + 1ull * WN;
        u16* Wkt = wt + 2ull * WN;
        u16* Wvt = wt + 3ull * WN;
        u16* Wqt = wt + 4ull * WN;

        // 0) convert W1, Wk, Wv, z
        wconv1<<<dim3(32, 32, 4), blk, 0, stream>>>(
            W1, Wk, Wv, W1t, Wkt, Wvt, z, zb);

        // 1) gemm_h | gemm_k | gemm_v (full-K, in-block epilogue) ∥ wconv W2,Wq
        mA<<<dim3(96 + 2048), blk, 0, stream>>>(
            zb, W1t, Wkt, Wvt, b1, bk, bv, hb, o_dK, ws_v, W2, Wq, W2t, Wqt);

        // 2) gemm_dz ∥ dv_write b<32
        mDZ<<<dim3(32 + 1024), blk, 0, stream>>>(
            hb, W2t, b2, o_dz, dzb, ws_v, o_dK, o_dV);

        // 3) dual gemm_q ∥ dv_write b>=32
        mQ<<<dim3(32 + 1024), blk, 0, stream>>>(
            zb, dzb, Wqt, bq, ws_q, ws_dq, ws_v, o_dK, o_dV);
    } else {
        // ------------------- f32 fallback path -------------------
        float* pool = ws + 4 * BD + 64;
        int KSf = 16;
        while (KSf > 1 &&
               ((size_t)(4 * BD + 64) + 2ull * KSf * BD) * 4ull > ws_size)
            KSf >>= 1;
        int kc = DD / KSf;
        float* p0 = pool;
        float* p1 = pool + (size_t)KSf * BD;

        dim3 gG(DD / 64, KSf);
        dim3 gG2(DD / 64, KSf, 2);
        dim3 gE(BD / 256);

        gemm64<<<gG, blk, 0, stream>>>(z, W1, p0, kc);
        epilogue_f32<<<gE, blk, 0, stream>>>(p0, b1, ws_h, 1, KSf);

        gemm64<<<gG, blk, 0, stream>>>(ws_h, W2, p0, kc);
        epilogue_f32<<<gE, blk, 0, stream>>>(p0, b2, o_dz, 0, KSf);

        gemm64_z2<<<gG2, blk, 0, stream>>>(z, Wk, Wv, p0, p1, kc);
        ep_kv_f32<<<gE, blk, 0, stream>>>(p0, p1, bk, bv, o_dK, ws_v, KSf);

        dv_write_full<<<dim3(BB * 32), blk, 0, stream>>>(ws_v, o_dK, o_dV);

        gemm128<<<gG, blk, 0, stream>>>(z, o_dz, Wq, p0, kc);
        ep_q_dq_f32<<<gE, blk, 0, stream>>>(p0, bq, ws_q, ws_dq, KSf);
    }

    // 4) a = q . dK ; da = a + dq . K   (tiny, L2-hot inputs)
    reduce_a_da<<<dim3(BB), blk, 0, stream>>>(ws_q, o_dK, ws_dq, Kin, ws_a, o_da);

    // 5) dc = v*a + V @ dq  — pure nt-read stream
    dc_dot<<<dim3(BB * 32), blk, 0, stream>>>(Vin, ws_v, ws_dq, ws_a, o_dc);
}